// Round 8
// baseline (2006.530 us; speedup 1.0000x reference)
//
#include <hip/hip_runtime.h>

// ---------------------------------------------------------------------------
// PointNet++ SetAbstraction MSG  (B=8, N=4096, S=1024, radii .1/.2, k 16/32)
// Pipeline: fps -> ballquery -> [G1 gemm -> stats -> G2 gemm(+pool minmax,
// +stats)] x2 -> pool_concat -> F1 -> stats -> F2 -> stats -> final write.
// FPS / ball-query distances use fp-contract OFF to bit-match the f32 ref.
// R5: packed-u64 argmax + DPP stages (1140->850us).  R6: full-DPP wave reduce
// via row_bcast15/31 (850->800us). VALUBusy now ~67%/CU: issue-bound at
// 2 waves/SIMD.
// R7: 1024 threads (4 pts/thread) -> 4 waves/SIMD: distance phase halves per
// wave, reduce chains interleave on the SIMD. Cross-wave scan widens to 16.
// ---------------------------------------------------------------------------

#define DEV __device__ __forceinline__

DEV float d2_nofma(float ax, float ay, float az, float bx, float by, float bz) {
#pragma clang fp contract(off)
  float dx = ax - bx, dy = ay - by, dz = az - bz;
  float s = dx * dx + dy * dy;
  return s + dz * dz;
}

DEV unsigned long long u64max(unsigned long long a, unsigned long long b) {
  return a > b ? a : b;
}

// ------------------------------ FPS ----------------------------------------
// one block per batch; 1024 threads x 4 points each. Packed-u64 argmax:
// value-bits<<32 | (4095-idx)  => max == first-max (min index on ties).
__global__ __launch_bounds__(1024) void fps_kernel(
    const float* __restrict__ xyz, int* __restrict__ idx_out,
    float* __restrict__ nx_ws, float* __restrict__ nx_out) {
  __shared__ float sp[4096 * 3];
  __shared__ int hist[1024];
  __shared__ unsigned long long cand[2][16];
  const int b = blockIdx.x, t = threadIdx.x;
  const int w = t >> 6;
  const float* P = xyz + (size_t)b * 12288;
  float px[4], py[4], pz[4], dd[4];
#pragma unroll
  for (int j = 0; j < 4; j++) {
    int pi = t * 4 + j;
    float x = P[pi * 3], y = P[pi * 3 + 1], z = P[pi * 3 + 2];
    px[j] = x; py[j] = y; pz[j] = z; dd[j] = 1e10f;
    sp[pi * 3] = x; sp[pi * 3 + 1] = y; sp[pi * 3 + 2] = z;
  }
  __syncthreads();
  int last = 0;
  for (int it = 0; it < 1024; ++it) {
    if (t == 0) hist[it] = last;
    if (it == 1023) break;
    float lx = sp[last * 3], ly = sp[last * 3 + 1], lz = sp[last * 3 + 2];
    float bv = -1.0f;
    int bi = 0;
#pragma unroll
    for (int j = 0; j < 4; j++) {
      float d = d2_nofma(px[j], py[j], pz[j], lx, ly, lz);
      float nd = fminf(dd[j], d);  // matches jnp.minimum
      dd[j] = nd;
      if (nd > bv) { bv = nd; bi = t * 4 + j; }  // strict > : first-max ties
    }
    // pack: dists >= 0 so f32 bits are order-preserving; (4095-bi) makes
    // u64-max pick the smallest index on value ties (matches argmax).
    unsigned long long p =
        ((unsigned long long)__float_as_uint(bv) << 32) |
        (unsigned int)(4095 - bi);
    // wave max-reduce, all DPP (VALU latency, no LDS pipe):
    //   xor1, xor2, ror4, ror8  -> each 16-lane row holds its row max
    //   row_bcast15, row_bcast31 -> lane 63 holds the wave max
    // bound_ctrl=0 with old=0: disabled lanes yield 0, never wins (p>=0).
#define DPP_MAX_STEP(CTRL)                                                  \
    {                                                                       \
      int lo_ = (int)(unsigned int)(p & 0xffffffffull);                     \
      int hi_ = (int)(unsigned int)(p >> 32);                               \
      int olo_ = __builtin_amdgcn_update_dpp(0, lo_, CTRL, 0xf, 0xf, false);\
      int ohi_ = __builtin_amdgcn_update_dpp(0, hi_, CTRL, 0xf, 0xf, false);\
      unsigned long long q_ =                                               \
          ((unsigned long long)(unsigned int)ohi_ << 32) |                  \
          (unsigned int)olo_;                                               \
      if (q_ > p) p = q_;                                                   \
    }
    DPP_MAX_STEP(0xB1);   // quad_perm [1,0,3,2]  : xor 1
    DPP_MAX_STEP(0x4E);   // quad_perm [2,3,0,1]  : xor 2
    DPP_MAX_STEP(0x124);  // row_ror:4
    DPP_MAX_STEP(0x128);  // row_ror:8   -> row-of-16 max everywhere
    DPP_MAX_STEP(0x142);  // row_bcast15 -> lanes 16-31,48-63 pairwise-merged
    DPP_MAX_STEP(0x143);  // row_bcast31 -> lane 63 = wave max
#undef DPP_MAX_STEP
    const int buf = it & 1;
    if ((t & 63) == 63) cand[buf][w] = p;
    __syncthreads();
    // redundant cross-wave pick, tree-shaped (dep depth 4, 16 waves)
    unsigned long long m0 = u64max(cand[buf][0], cand[buf][1]);
    unsigned long long m1 = u64max(cand[buf][2], cand[buf][3]);
    unsigned long long m2 = u64max(cand[buf][4], cand[buf][5]);
    unsigned long long m3 = u64max(cand[buf][6], cand[buf][7]);
    unsigned long long m4 = u64max(cand[buf][8], cand[buf][9]);
    unsigned long long m5 = u64max(cand[buf][10], cand[buf][11]);
    unsigned long long m6 = u64max(cand[buf][12], cand[buf][13]);
    unsigned long long m7 = u64max(cand[buf][14], cand[buf][15]);
    unsigned long long best =
        u64max(u64max(u64max(m0, m1), u64max(m2, m3)),
               u64max(u64max(m4, m5), u64max(m6, m7)));
    last = 4095 - (int)(unsigned int)(best & 0xffffffffull);
  }
  __syncthreads();
  // epilogue: one-time writes (one center per thread)
  {
    int i = t;
    if (i < 1024) {
      int id = hist[i];
      idx_out[(size_t)b * 1024 + i] = id;
      float x = sp[id * 3], y = sp[id * 3 + 1], z = sp[id * 3 + 2];
      size_t o = ((size_t)b * 1024 + i) * 3;
      nx_ws[o] = x; nx_ws[o + 1] = y; nx_ws[o + 2] = z;
      nx_out[o] = x; nx_out[o + 1] = y; nx_out[o + 2] = z;
    }
  }
}

// --------------------------- Ball query ------------------------------------
// one wave per center; both radii in one pass; first-k ascending + pad-first
__global__ __launch_bounds__(256) void bq_kernel(
    const float* __restrict__ xyz, const float* __restrict__ nx,
    int* __restrict__ out0, int* __restrict__ out1) {
  const int wv = threadIdx.x >> 6, lane = threadIdx.x & 63;
  const int bs = blockIdx.x * 4 + wv;  // 8192 centers
  const int b = bs >> 10;
  const float* c = nx + (size_t)bs * 3;
  const float cx = c[0], cy = c[1], cz = c[2];
  const float* P = xyz + (size_t)b * 12288;
  const float rr0 = 0.1f * 0.1f, rr1 = 0.2f * 0.2f;
  int c0 = 0, c1 = 0, f0 = -1, f1 = -1;
  const unsigned long long below = (1ull << lane) - 1ull;
  for (int base = 0; base < 4096; base += 64) {
    int p = base + lane;
    float x = P[p * 3], y = P[p * 3 + 1], z = P[p * 3 + 2];
    float d2 = d2_nofma(cx, cy, cz, x, y, z);
    bool in0 = d2 < rr0, in1 = d2 < rr1;
    unsigned long long m0 = __ballot(in0), m1 = __ballot(in1);
    if (in0) {
      int slot = c0 + __popcll(m0 & below);
      if (slot < 16) out0[(size_t)bs * 16 + slot] = p;
    }
    if (in1) {
      int slot = c1 + __popcll(m1 & below);
      if (slot < 32) out1[(size_t)bs * 32 + slot] = p;
    }
    if (f0 < 0 && m0) f0 = base + __ffsll(m0) - 1;
    if (f1 < 0 && m1) f1 = base + __ffsll(m1) - 1;
    c0 += __popcll(m0);
    c1 += __popcll(m1);
    if (c0 >= 16 && c1 >= 32) break;
  }
  if (c0 < 16 && lane >= c0 && lane < 16) out0[(size_t)bs * 16 + lane] = f0;
  if (c1 < 32 && lane >= c1 && lane < 32) out1[(size_t)bs * 32 + lane] = f1;
}

// ------------------------ G1: gather + GEMM (K=67,N=128) --------------------
// BM=128, 256 thr, 8x8 micro (interleaved 4+4 rows/cols), K chunked 34+33
template <int KS>
__global__ __launch_bounds__(256) void g1_kernel(
    const float* __restrict__ xyz, const float* __restrict__ feat,
    const float* __restrict__ nx, const int* __restrict__ idx,
    const float* __restrict__ w1, float* __restrict__ y1) {
  __shared__ float At[34][132];
  __shared__ float Bt[34][132];
  const int t = threadIdx.x;
  const int g0 = blockIdx.x * 128;
  const int tx = t & 15, ty = t >> 4;
  const int r = t >> 1, half = t & 1;
  const int g = g0 + r;
  const int bs = g / KS;
  const int b = bs >> 10;
  const int id = idx[g];
  const float* fp = feat + ((size_t)(b * 4096 + id)) * 64;
  float rel0 = 0, rel1 = 0, rel2 = 0;
  if (half == 0) {
    const float* cp = nx + (size_t)bs * 3;
    const float* pp = xyz + ((size_t)(b * 4096 + id)) * 3;
    rel0 = pp[0] - cp[0]; rel1 = pp[1] - cp[1]; rel2 = pp[2] - cp[2];
  }
  float acc[8][8];
#pragma unroll
  for (int i = 0; i < 8; i++)
#pragma unroll
    for (int j = 0; j < 8; j++) acc[i][j] = 0.f;

#pragma unroll
  for (int kc = 0; kc < 2; ++kc) {
    const int kb = kc * 34;
    const int kn = kc ? 33 : 34;
    {  // stage A (gathered rows, rel-xyz then feat)
      int c0 = half * 17;
      int cn = half ? (kn - 17) : 17;
      for (int u = 0; u < cn; u++) {
        int cabs = kb + c0 + u;
        float v;
        if (cabs < 3) v = (cabs == 0) ? rel0 : ((cabs == 1) ? rel1 : rel2);
        else v = fp[cabs - 3];
        At[c0 + u][r] = v;
      }
    }
    {  // stage B (w1 transposed)
      int o = t >> 1;
      const float* wp = w1 + (size_t)o * 67;
      int c0 = half * 17;
      int cn = half ? (kn - 17) : 17;
      for (int u = 0; u < cn; u++) Bt[c0 + u][o] = wp[kb + c0 + u];
    }
    __syncthreads();
#pragma unroll 4
    for (int k = 0; k < kn; k++) {
      float4 a0 = *(const float4*)&At[k][ty * 4];
      float4 a1 = *(const float4*)&At[k][ty * 4 + 64];
      float4 b0 = *(const float4*)&Bt[k][tx * 4];
      float4 b1 = *(const float4*)&Bt[k][tx * 4 + 64];
      float av[8] = {a0.x, a0.y, a0.z, a0.w, a1.x, a1.y, a1.z, a1.w};
      float bv[8] = {b0.x, b0.y, b0.z, b0.w, b1.x, b1.y, b1.z, b1.w};
#pragma unroll
      for (int i = 0; i < 8; i++)
#pragma unroll
        for (int j = 0; j < 8; j++) acc[i][j] = fmaf(av[i], bv[j], acc[i][j]);
    }
    __syncthreads();
  }
#pragma unroll
  for (int i = 0; i < 8; i++) {
    int R = ty * 4 + (i & 3) + ((i >> 2) << 6);
    float4 s0 = {acc[i][0], acc[i][1], acc[i][2], acc[i][3]};
    float4 s1 = {acc[i][4], acc[i][5], acc[i][6], acc[i][7]};
    *(float4*)&y1[((size_t)(g0 + R)) * 128 + tx * 4] = s0;
    *(float4*)&y1[((size_t)(g0 + R)) * 128 + tx * 4 + 64] = s1;
  }
}

// ---- G2: affine+relu fused GEMM (K=128,N=256) + channel stats + pool minmax
template <int KS>
__global__ __launch_bounds__(256, 2) void g2_kernel(
    const float* __restrict__ y1, const float* __restrict__ w2,
    const float* __restrict__ a1, const float* __restrict__ b1,
    float* __restrict__ pmin, float* __restrict__ pmax,
    float* __restrict__ statp) {
  __shared__ float At[32][132];
  __shared__ float Bt[32][260];
  const int t = threadIdx.x;
  const int g0 = blockIdx.x * 128;
  const int tx = t & 15, ty = t >> 4;
  float acc[8][16];
#pragma unroll
  for (int i = 0; i < 8; i++)
#pragma unroll
    for (int j = 0; j < 16; j++) acc[i][j] = 0.f;

  const int r = t >> 1, halfA = t & 1;
  const float* arow = y1 + (size_t)(g0 + r) * 128;
  for (int kc = 0; kc < 4; kc++) {
    {  // stage A with bn-affine + relu
      const int cb = kc * 32 + halfA * 16;
#pragma unroll
      for (int q = 0; q < 4; q++) {
        float4 v = *(const float4*)&arow[cb + q * 4];
        float vv[4] = {v.x, v.y, v.z, v.w};
#pragma unroll
        for (int e = 0; e < 4; e++) {
          int cabs = cb + q * 4 + e;
          float x = fmaxf(fmaf(a1[cabs], vv[e], b1[cabs]), 0.f);
          At[halfA * 16 + q * 4 + e][r] = x;
        }
      }
    }
    {  // stage B (w2 transposed)
      const float* wrow = w2 + (size_t)t * 128 + kc * 32;
#pragma unroll
      for (int q = 0; q < 8; q++) {
        float4 w4 = *(const float4*)&wrow[q * 4];
        Bt[q * 4 + 0][t] = w4.x; Bt[q * 4 + 1][t] = w4.y;
        Bt[q * 4 + 2][t] = w4.z; Bt[q * 4 + 3][t] = w4.w;
      }
    }
    __syncthreads();
#pragma unroll 4
    for (int k = 0; k < 32; k++) {
      float4 a0 = *(const float4*)&At[k][ty * 4];
      float4 a1v = *(const float4*)&At[k][ty * 4 + 64];
      float4 b0 = *(const float4*)&Bt[k][tx * 4];
      float4 b1v = *(const float4*)&Bt[k][tx * 4 + 64];
      float4 b2v = *(const float4*)&Bt[k][tx * 4 + 128];
      float4 b3v = *(const float4*)&Bt[k][tx * 4 + 192];
      float av[8] = {a0.x, a0.y, a0.z, a0.w, a1v.x, a1v.y, a1v.z, a1v.w};
      float bv[16] = {b0.x, b0.y, b0.z, b0.w, b1v.x, b1v.y, b1v.z, b1v.w,
                      b2v.x, b2v.y, b2v.z, b2v.w, b3v.x, b3v.y, b3v.z, b3v.w};
#pragma unroll
      for (int i = 0; i < 8; i++)
#pragma unroll
        for (int j = 0; j < 16; j++) acc[i][j] = fmaf(av[i], bv[j], acc[i][j]);
    }
    __syncthreads();
  }

  // -------- reductions: SUM, SQ (stats) ; MIN, MAX (pooling) --------
  float* red = &At[0][0];  // 4224 floats >= 2048 needed
  const int w = t >> 6;
  const bool wrsel = ((t & 48) == 0);
  const int NS = 128 / KS;  // s-groups per block

  // SUM
#pragma unroll
  for (int h = 0; h < 2; h++)
#pragma unroll
    for (int j = 0; j < 16; j++) {
      float x = acc[h * 4][j] + acc[h * 4 + 1][j] + acc[h * 4 + 2][j] + acc[h * 4 + 3][j];
      x += __shfl_xor(x, 16);
      x += __shfl_xor(x, 32);
      if (wrsel) red[(((w << 1) | h) << 8) + (tx << 2) + (j & 3) + ((j >> 2) << 6)] = x;
    }
  __syncthreads();
  float psum = 0;
  for (int e = 0; e < 8; e++) psum += red[(e << 8) + t];
  __syncthreads();
  // SQ
#pragma unroll
  for (int h = 0; h < 2; h++)
#pragma unroll
    for (int j = 0; j < 16; j++) {
      float x = acc[h * 4][j] * acc[h * 4][j];
      x = fmaf(acc[h * 4 + 1][j], acc[h * 4 + 1][j], x);
      x = fmaf(acc[h * 4 + 2][j], acc[h * 4 + 2][j], x);
      x = fmaf(acc[h * 4 + 3][j], acc[h * 4 + 3][j], x);
      x += __shfl_xor(x, 16);
      x += __shfl_xor(x, 32);
      if (wrsel) red[(((w << 1) | h) << 8) + (tx << 2) + (j & 3) + ((j >> 2) << 6)] = x;
    }
  __syncthreads();
  float psq = 0;
  for (int e = 0; e < 8; e++) psq += red[(e << 8) + t];
  statp[(size_t)blockIdx.x * 512 + t] = psum;
  statp[(size_t)blockIdx.x * 512 + 256 + t] = psq;
  __syncthreads();
  // MIN
#pragma unroll
  for (int h = 0; h < 2; h++)
#pragma unroll
    for (int j = 0; j < 16; j++) {
      float x = fminf(fminf(acc[h * 4][j], acc[h * 4 + 1][j]),
                      fminf(acc[h * 4 + 2][j], acc[h * 4 + 3][j]));
      x = fminf(x, __shfl_xor(x, 16));
      x = fminf(x, __shfl_xor(x, 32));
      if (wrsel) red[(((w << 1) | h) << 8) + (tx << 2) + (j & 3) + ((j >> 2) << 6)] = x;
    }
  __syncthreads();
  for (int cell = t; cell < NS * 256; cell += 256) {
    int sg = cell >> 8, col = cell & 255;
    float val;
    if (KS == 16) {
      int h = sg >> 2, ww = sg & 3;
      val = red[(((ww << 1) | h) << 8) + col];
    } else {
      int h = sg >> 1, w0 = (sg & 1) << 1;
      val = fminf(red[(((w0 << 1) | h) << 8) + col],
                  red[((((w0 + 1) << 1) | h) << 8) + col]);
    }
    pmin[(size_t)(blockIdx.x * NS + sg) * 256 + col] = val;
  }
  __syncthreads();
  // MAX
#pragma unroll
  for (int h = 0; h < 2; h++)
#pragma unroll
    for (int j = 0; j < 16; j++) {
      float x = fmaxf(fmaxf(acc[h * 4][j], acc[h * 4 + 1][j]),
                      fmaxf(acc[h * 4 + 2][j], acc[h * 4 + 3][j]));
      x = fmaxf(x, __shfl_xor(x, 16));
      x = fmaxf(x, __shfl_xor(x, 32));
      if (wrsel) red[(((w << 1) | h) << 8) + (tx << 2) + (j & 3) + ((j >> 2) << 6)] = x;
    }
  __syncthreads();
  for (int cell = t; cell < NS * 256; cell += 256) {
    int sg = cell >> 8, col = cell & 255;
    float val;
    if (KS == 16) {
      int h = sg >> 2, ww = sg & 3;
      val = red[(((ww << 1) | h) << 8) + col];
    } else {
      int h = sg >> 1, w0 = (sg & 1) << 1;
      val = fmaxf(red[(((w0 << 1) | h) << 8) + col],
                  red[((((w0 + 1) << 1) | h) << 8) + col]);
    }
    pmax[(size_t)(blockIdx.x * NS + sg) * 256 + col] = val;
  }
}

// ------------------- channel stats partials over [M][N] ---------------------
__global__ __launch_bounds__(256) void stats_partial(
    const float* __restrict__ x, float* __restrict__ statp, int M, int N) {
  const int nb = gridDim.x;
  const int rows = M / nb;
  const int r0 = blockIdx.x * rows;
  const int t = threadIdx.x;
  const int col = t & (N - 1);
  const int sub = t / N;
  const int nsub = 256 / N;
  float s = 0, q = 0;
  for (int rr = sub; rr < rows; rr += nsub) {
    float v = x[(size_t)(r0 + rr) * N + col];
    s += v;
    q = fmaf(v, v, q);
  }
  if (N == 256) {
    statp[(size_t)blockIdx.x * 512 + col] = s;
    statp[(size_t)blockIdx.x * 512 + 256 + col] = q;
  } else {
    __shared__ float ss[256], qq[256];
    ss[t] = s; qq[t] = q;
    __syncthreads();
    if (t < 128) {
      statp[(size_t)blockIdx.x * 256 + t] = ss[t] + ss[t + 128];
      statp[(size_t)blockIdx.x * 256 + 128 + t] = qq[t] + qq[t + 128];
    }
  }
}

// ------------- reduce partials -> per-channel affine (a,b) ------------------
__global__ __launch_bounds__(256) void finalize_affine(
    const float* __restrict__ statp, int nb, float invM,
    const float* __restrict__ gamma, const float* __restrict__ beta,
    float* __restrict__ aout, float* __restrict__ bout, int N) {
  const int c = blockIdx.x;
  const int t = threadIdx.x;
  float s = 0, q = 0;
  for (int i = t; i < nb; i += 256) {
    s += statp[(size_t)i * 2 * N + c];
    q += statp[(size_t)i * 2 * N + N + c];
  }
#pragma unroll
  for (int m = 1; m <= 32; m <<= 1) {
    s += __shfl_xor(s, m);
    q += __shfl_xor(q, m);
  }
  __shared__ float rs[4], rq[4];
  if ((t & 63) == 0) { rs[t >> 6] = s; rq[t >> 6] = q; }
  __syncthreads();
  if (t == 0) {
    s = rs[0] + rs[1] + rs[2] + rs[3];
    q = rq[0] + rq[1] + rq[2] + rq[3];
    float mean = s * invM;
    float var = q * invM - mean * mean;
    float ia = gamma[c] * rsqrtf(var + 1e-5f);
    aout[c] = ia;
    bout[c] = beta[c] - mean * ia;
  }
}

// --------- pooled minmax + affine -> concat activation [8192][512] ----------
__global__ __launch_bounds__(256) void pool_concat(
    const float* __restrict__ pmin, const float* __restrict__ pmax,
    const float* __restrict__ a2, const float* __restrict__ b2,
    float* __restrict__ cat, int off) {
  int i = blockIdx.x * 256 + threadIdx.x;  // 8192*256
  int row = i >> 8, c = i & 255;
  float a = a2[c];
  float v = (a > 0.f) ? pmax[i] : pmin[i];  // max(relu(a*x+b)) = relu(a*ext+b)
  cat[(size_t)row * 512 + off + c] = fmaxf(fmaf(a, v, b2[c]), 0.f);
}

// ---------------- fuse GEMMs: M=8192, N=256 (2 col blocks of 128) -----------
template <bool AFF>
__global__ __launch_bounds__(256) void f_kernel(
    const float* __restrict__ A, const float* __restrict__ W,
    const float* __restrict__ ain, const float* __restrict__ bin,
    float* __restrict__ Y, int K) {
  __shared__ float At[64][68];
  __shared__ float Bt[64][132];
  const int t = threadIdx.x, tx = t & 15, ty = t >> 4;
  const int g0 = blockIdx.x * 64, cb = blockIdx.y;
  float acc[4][8];
#pragma unroll
  for (int i = 0; i < 4; i++)
#pragma unroll
    for (int j = 0; j < 8; j++) acc[i][j] = 0.f;
  const int rA = t >> 2, qA = t & 3;
  const int oB = t >> 1, hB = t & 1;
  const float* arow = A + (size_t)(g0 + rA) * K + qA * 16;
  const float* wrow = W + (size_t)(cb * 128 + oB) * K + hB * 32;
  for (int kc = 0; kc < K; kc += 64) {
    {
#pragma unroll
      for (int q = 0; q < 4; q++) {
        float4 v = *(const float4*)&arow[kc + q * 4];
        float vv[4] = {v.x, v.y, v.z, v.w};
        if constexpr (AFF) {
          int c = kc + qA * 16 + q * 4;
#pragma unroll
          for (int e = 0; e < 4; e++)
            vv[e] = fmaxf(fmaf(ain[c + e], vv[e], bin[c + e]), 0.f);
        }
#pragma unroll
        for (int e = 0; e < 4; e++) At[qA * 16 + q * 4 + e][rA] = vv[e];
      }
    }
    {
#pragma unroll
      for (int q = 0; q < 8; q++) {
        float4 v = *(const float4*)&wrow[kc + q * 4];
        Bt[hB * 32 + q * 4 + 0][oB] = v.x;
        Bt[hB * 32 + q * 4 + 1][oB] = v.y;
        Bt[hB * 32 + q * 4 + 2][oB] = v.z;
        Bt[hB * 32 + q * 4 + 3][oB] = v.w;
      }
    }
    __syncthreads();
#pragma unroll 8
    for (int k = 0; k < 64; k++) {
      float4 a0 = *(const float4*)&At[k][ty * 4];
      float4 b0 = *(const float4*)&Bt[k][tx * 4];
      float4 b1 = *(const float4*)&Bt[k][tx * 4 + 64];
      float av[4] = {a0.x, a0.y, a0.z, a0.w};
      float bv[8] = {b0.x, b0.y, b0.z, b0.w, b1.x, b1.y, b1.z, b1.w};
#pragma unroll
      for (int i = 0; i < 4; i++)
#pragma unroll
        for (int j = 0; j < 8; j++) acc[i][j] = fmaf(av[i], bv[j], acc[i][j]);
    }
    __syncthreads();
  }
#pragma unroll
  for (int i = 0; i < 4; i++) {
    int R = g0 + ty * 4 + i;
    float4 s0 = {acc[i][0], acc[i][1], acc[i][2], acc[i][3]};
    float4 s1 = {acc[i][4], acc[i][5], acc[i][6], acc[i][7]};
    *(float4*)&Y[(size_t)R * 256 + cb * 128 + tx * 4] = s0;
    *(float4*)&Y[(size_t)R * 256 + cb * 128 + tx * 4 + 64] = s1;
  }
}

// ------------------------------ final write --------------------------------
__global__ __launch_bounds__(256) void final_write(
    const float* __restrict__ y, const float* __restrict__ a,
    const float* __restrict__ b, float* __restrict__ out) {
  int i = blockIdx.x * 256 + threadIdx.x;
  int c = i & 255;
  out[i] = fmaxf(fmaf(a[c], y[i], b[c]), 0.f);
}

// ---------------------------------------------------------------------------
// ws layout (float offsets)
static const size_t OFF_IDXFPS = 0;         //  8192 (int)
static const size_t OFF_NEWXYZ = 8192;      // 24576
static const size_t OFF_IDX0 = 32768;       // 131072 (int)
static const size_t OFF_IDX1 = 163840;      // 262144 (int)
static const size_t OFF_Y1 = 425984;        // 33554432
static const size_t OFF_PMIN = 33980416;    // 2097152
static const size_t OFF_PMAX = 36077568;    // 2097152
static const size_t OFF_STATP = 38174720;   // 1048576
static const size_t OFF_CONCAT = 39223296;  // 4194304
static const size_t OFF_YF1 = 43417600;     // 2097152
static const size_t OFF_YF2 = 45514752;     // 2097152
static const size_t OFF_AFF = 47611904;     // 2048

extern "C" void kernel_launch(void* const* d_in, const int* in_sizes, int n_in,
                              void* d_out, int out_size, void* d_ws,
                              size_t ws_size, hipStream_t stream) {
  const float* xyz = (const float*)d_in[0];
  const float* feat = (const float*)d_in[1];
  const float* w1_0 = (const float*)d_in[2];
  const float* g1_0 = (const float*)d_in[3];
  const float* b1_0 = (const float*)d_in[4];
  const float* w2_0 = (const float*)d_in[5];
  const float* g2_0 = (const float*)d_in[6];
  const float* b2_0 = (const float*)d_in[7];
  const float* w1_1 = (const float*)d_in[8];
  const float* g1_1 = (const float*)d_in[9];
  const float* b1_1 = (const float*)d_in[10];
  const float* w2_1 = (const float*)d_in[11];
  const float* g2_1 = (const float*)d_in[12];
  const float* b2_1 = (const float*)d_in[13];
  const float* wf1 = (const float*)d_in[14];
  const float* gf1 = (const float*)d_in[15];
  const float* bf1 = (const float*)d_in[16];
  const float* wf2 = (const float*)d_in[17];
  const float* gf2 = (const float*)d_in[18];
  const float* bf2 = (const float*)d_in[19];

  float* out = (float*)d_out;
  float* ws = (float*)d_ws;

  int* idxfps = (int*)(ws + OFF_IDXFPS);
  float* nx = ws + OFF_NEWXYZ;
  int* idx0 = (int*)(ws + OFF_IDX0);
  int* idx1 = (int*)(ws + OFF_IDX1);
  float* y1 = ws + OFF_Y1;
  float* pmin = ws + OFF_PMIN;
  float* pmax = ws + OFF_PMAX;
  float* statp = ws + OFF_STATP;
  float* cat = ws + OFF_CONCAT;
  float* yf1 = ws + OFF_YF1;
  float* yf2 = ws + OFF_YF2;
  float* a1 = ws + OFF_AFF;
  float* b1 = a1 + 128;
  float* a2 = b1 + 128;
  float* b2 = a2 + 256;
  float* af1 = b2 + 256;
  float* bf1a = af1 + 256;
  float* af2 = bf1a + 256;
  float* bf2a = af2 + 256;

  fps_kernel<<<8, 1024, 0, stream>>>(xyz, idxfps, nx, out);
  bq_kernel<<<2048, 256, 0, stream>>>(xyz, nx, idx0, idx1);

  // branch 0 (r=0.1, k=16): M=131072
  g1_kernel<16><<<1024, 256, 0, stream>>>(xyz, feat, nx, idx0, w1_0, y1);
  stats_partial<<<1024, 256, 0, stream>>>(y1, statp, 131072, 128);
  finalize_affine<<<128, 256, 0, stream>>>(statp, 1024, 1.f / 131072.f, g1_0, b1_0, a1, b1, 128);
  g2_kernel<16><<<1024, 256, 0, stream>>>(y1, w2_0, a1, b1, pmin, pmax, statp);
  finalize_affine<<<256, 256, 0, stream>>>(statp, 1024, 1.f / 131072.f, g2_0, b2_0, a2, b2, 256);
  pool_concat<<<8192, 256, 0, stream>>>(pmin, pmax, a2, b2, cat, 0);

  // branch 1 (r=0.2, k=32): M=262144
  g1_kernel<32><<<2048, 256, 0, stream>>>(xyz, feat, nx, idx1, w1_1, y1);
  stats_partial<<<1024, 256, 0, stream>>>(y1, statp, 262144, 128);
  finalize_affine<<<128, 256, 0, stream>>>(statp, 1024, 1.f / 262144.f, g1_1, b1_1, a1, b1, 128);
  g2_kernel<32><<<2048, 256, 0, stream>>>(y1, w2_1, a1, b1, pmin, pmax, statp);
  finalize_affine<<<256, 256, 0, stream>>>(statp, 2048, 1.f / 262144.f, g2_1, b2_1, a2, b2, 256);
  pool_concat<<<8192, 256, 0, stream>>>(pmin, pmax, a2, b2, cat, 256);

  // fuse MLP
  f_kernel<false><<<dim3(128, 2), 256, 0, stream>>>(cat, wf1, nullptr, nullptr, yf1, 512);
  stats_partial<<<1024, 256, 0, stream>>>(yf1, statp, 8192, 256);
  finalize_affine<<<256, 256, 0, stream>>>(statp, 1024, 1.f / 8192.f, gf1, bf1, af1, bf1a, 256);
  f_kernel<true><<<dim3(128, 2), 256, 0, stream>>>(yf1, wf2, af1, bf1a, yf2, 256);
  stats_partial<<<1024, 256, 0, stream>>>(yf2, statp, 8192, 256);
  finalize_affine<<<256, 256, 0, stream>>>(statp, 1024, 1.f / 8192.f, gf2, bf2, af2, bf2a, 256);
  final_write<<<8192, 256, 0, stream>>>(yf2, af2, bf2a, out + 24576);
}

// Round 9
// 1386.378 us; speedup vs baseline: 1.4473x; 1.4473x over previous
//
#include <hip/hip_runtime.h>

// ---------------------------------------------------------------------------
// PointNet++ SetAbstraction MSG  (B=8, N=4096, S=1024, radii .1/.2, k 16/32)
// fps -> ballquery -> [G1(+stats fused) -> affine -> G2(+stats+pool)] x2
//   -> pool_concat -> F1(+stats) -> affine -> F2(+stats) -> final write.
// FPS / ball-query distances use fp-contract OFF to bit-match the f32 ref.
// R5: packed-u64 argmax + DPP (1140->850). R6: full-DPP reduce (850->800).
// R7: 1024thr REGRESSED (1293): barrier cost scales with wave count; 512thr
// 8-wave is the structural floor for 1-CU/batch FPS. R8: revert fps to R6
// (+fmax-tree argmax, bit-identical); fuse channel stats into g1/f kernels
// (kills 4 stats_partial launches + 192MB of y1 re-reads).
// ---------------------------------------------------------------------------

#define DEV __device__ __forceinline__

DEV float d2_nofma(float ax, float ay, float az, float bx, float by, float bz) {
#pragma clang fp contract(off)
  float dx = ax - bx, dy = ay - by, dz = az - bz;
  float s = dx * dx + dy * dy;
  return s + dz * dz;
}

DEV unsigned long long u64max(unsigned long long a, unsigned long long b) {
  return a > b ? a : b;
}

// ------------------------------ FPS ----------------------------------------
// one block per batch; 512 threads x 8 points. Packed-u64 argmax:
// value-bits<<32 | (4095-idx) => max == first-max (min index on ties).
__global__ __launch_bounds__(512) void fps_kernel(
    const float* __restrict__ xyz, int* __restrict__ idx_out,
    float* __restrict__ nx_ws, float* __restrict__ nx_out) {
  __shared__ float sp[4096 * 3];
  __shared__ int hist[1024];
  __shared__ unsigned long long cand[2][8];
  const int b = blockIdx.x, t = threadIdx.x;
  const int w = t >> 6;
  const float* P = xyz + (size_t)b * 12288;
  float px[8], py[8], pz[8], dd[8];
#pragma unroll
  for (int j = 0; j < 8; j++) {
    int pi = t * 8 + j;
    float x = P[pi * 3], y = P[pi * 3 + 1], z = P[pi * 3 + 2];
    px[j] = x; py[j] = y; pz[j] = z; dd[j] = 1e10f;
    sp[pi * 3] = x; sp[pi * 3 + 1] = y; sp[pi * 3 + 2] = z;
  }
  __syncthreads();
  int last = 0;
  for (int it = 0; it < 1024; ++it) {
    if (t == 0) hist[it] = last;
    if (it == 1023) break;
    float lx = sp[last * 3], ly = sp[last * 3 + 1], lz = sp[last * 3 + 2];
#pragma unroll
    for (int j = 0; j < 8; j++) {
      float d = d2_nofma(px[j], py[j], pz[j], lx, ly, lz);
      dd[j] = fminf(dd[j], d);  // matches jnp.minimum
    }
    // fmax tree (depth 3) + lowest-match => identical to strict-> first-max
    float bv = fmaxf(fmaxf(fmaxf(dd[0], dd[1]), fmaxf(dd[2], dd[3])),
                     fmaxf(fmaxf(dd[4], dd[5]), fmaxf(dd[6], dd[7])));
    int bj = 7;
#pragma unroll
    for (int j = 6; j >= 0; j--) bj = (dd[j] == bv) ? j : bj;
    int bi = t * 8 + bj;
    // pack: dists >= 0 so f32 bits are order-preserving; (4095-bi) makes
    // u64-max pick the smallest index on value ties (matches argmax).
    unsigned long long p =
        ((unsigned long long)__float_as_uint(bv) << 32) |
        (unsigned int)(4095 - bi);
    // wave max-reduce, all DPP (VALU latency, no LDS pipe). bound_ctrl=0
    // with old=0: disabled lanes yield 0, never wins (p>=0).
#define DPP_MAX_STEP(CTRL)                                                  \
    {                                                                       \
      int lo_ = (int)(unsigned int)(p & 0xffffffffull);                     \
      int hi_ = (int)(unsigned int)(p >> 32);                               \
      int olo_ = __builtin_amdgcn_update_dpp(0, lo_, CTRL, 0xf, 0xf, false);\
      int ohi_ = __builtin_amdgcn_update_dpp(0, hi_, CTRL, 0xf, 0xf, false);\
      unsigned long long q_ =                                               \
          ((unsigned long long)(unsigned int)ohi_ << 32) |                  \
          (unsigned int)olo_;                                               \
      if (q_ > p) p = q_;                                                   \
    }
    DPP_MAX_STEP(0xB1);   // quad_perm xor1
    DPP_MAX_STEP(0x4E);   // quad_perm xor2
    DPP_MAX_STEP(0x124);  // row_ror:4
    DPP_MAX_STEP(0x128);  // row_ror:8   -> row-of-16 max everywhere
    DPP_MAX_STEP(0x142);  // row_bcast15
    DPP_MAX_STEP(0x143);  // row_bcast31 -> lane 63 = wave max
#undef DPP_MAX_STEP
    const int buf = it & 1;
    if ((t & 63) == 63) cand[buf][w] = p;
    __syncthreads();
    unsigned long long c0 = cand[buf][0], c1 = cand[buf][1];
    unsigned long long c2 = cand[buf][2], c3 = cand[buf][3];
    unsigned long long c4 = cand[buf][4], c5 = cand[buf][5];
    unsigned long long c6 = cand[buf][6], c7 = cand[buf][7];
    unsigned long long best =
        u64max(u64max(u64max(c0, c1), u64max(c2, c3)),
               u64max(u64max(c4, c5), u64max(c6, c7)));
    last = 4095 - (int)(unsigned int)(best & 0xffffffffull);
  }
  __syncthreads();
  // epilogue: one-time writes
  for (int i = t; i < 1024; i += 512) {
    int id = hist[i];
    idx_out[(size_t)b * 1024 + i] = id;
    float x = sp[id * 3], y = sp[id * 3 + 1], z = sp[id * 3 + 2];
    size_t o = ((size_t)b * 1024 + i) * 3;
    nx_ws[o] = x; nx_ws[o + 1] = y; nx_ws[o + 2] = z;
    nx_out[o] = x; nx_out[o + 1] = y; nx_out[o + 2] = z;
  }
}

// --------------------------- Ball query ------------------------------------
__global__ __launch_bounds__(256) void bq_kernel(
    const float* __restrict__ xyz, const float* __restrict__ nx,
    int* __restrict__ out0, int* __restrict__ out1) {
  const int wv = threadIdx.x >> 6, lane = threadIdx.x & 63;
  const int bs = blockIdx.x * 4 + wv;  // 8192 centers
  const int b = bs >> 10;
  const float* c = nx + (size_t)bs * 3;
  const float cx = c[0], cy = c[1], cz = c[2];
  const float* P = xyz + (size_t)b * 12288;
  const float rr0 = 0.1f * 0.1f, rr1 = 0.2f * 0.2f;
  int c0 = 0, c1 = 0, f0 = -1, f1 = -1;
  const unsigned long long below = (1ull << lane) - 1ull;
  for (int base = 0; base < 4096; base += 64) {
    int p = base + lane;
    float x = P[p * 3], y = P[p * 3 + 1], z = P[p * 3 + 2];
    float d2 = d2_nofma(cx, cy, cz, x, y, z);
    bool in0 = d2 < rr0, in1 = d2 < rr1;
    unsigned long long m0 = __ballot(in0), m1 = __ballot(in1);
    if (in0) {
      int slot = c0 + __popcll(m0 & below);
      if (slot < 16) out0[(size_t)bs * 16 + slot] = p;
    }
    if (in1) {
      int slot = c1 + __popcll(m1 & below);
      if (slot < 32) out1[(size_t)bs * 32 + slot] = p;
    }
    if (f0 < 0 && m0) f0 = base + __ffsll(m0) - 1;
    if (f1 < 0 && m1) f1 = base + __ffsll(m1) - 1;
    c0 += __popcll(m0);
    c1 += __popcll(m1);
    if (c0 >= 16 && c1 >= 32) break;
  }
  if (c0 < 16 && lane >= c0 && lane < 16) out0[(size_t)bs * 16 + lane] = f0;
  if (c1 < 32 && lane >= c1 && lane < 32) out1[(size_t)bs * 32 + lane] = f1;
}

// ------ G1: gather + GEMM (K=67,N=128) + FUSED column stats partials --------
template <int KS>
__global__ __launch_bounds__(256) void g1_kernel(
    const float* __restrict__ xyz, const float* __restrict__ feat,
    const float* __restrict__ nx, const int* __restrict__ idx,
    const float* __restrict__ w1, float* __restrict__ y1,
    float* __restrict__ statp) {
  __shared__ float At[34][132];
  __shared__ float Bt[34][132];
  const int t = threadIdx.x;
  const int g0 = blockIdx.x * 128;
  const int tx = t & 15, ty = t >> 4;
  const int r = t >> 1, half = t & 1;
  const int g = g0 + r;
  const int bs = g / KS;
  const int b = bs >> 10;
  const int id = idx[g];
  const float* fp = feat + ((size_t)(b * 4096 + id)) * 64;
  float rel0 = 0, rel1 = 0, rel2 = 0;
  if (half == 0) {
    const float* cp = nx + (size_t)bs * 3;
    const float* pp = xyz + ((size_t)(b * 4096 + id)) * 3;
    rel0 = pp[0] - cp[0]; rel1 = pp[1] - cp[1]; rel2 = pp[2] - cp[2];
  }
  float acc[8][8];
#pragma unroll
  for (int i = 0; i < 8; i++)
#pragma unroll
    for (int j = 0; j < 8; j++) acc[i][j] = 0.f;

#pragma unroll
  for (int kc = 0; kc < 2; ++kc) {
    const int kb = kc * 34;
    const int kn = kc ? 33 : 34;
    {
      int c0 = half * 17;
      int cn = half ? (kn - 17) : 17;
      for (int u = 0; u < cn; u++) {
        int cabs = kb + c0 + u;
        float v;
        if (cabs < 3) v = (cabs == 0) ? rel0 : ((cabs == 1) ? rel1 : rel2);
        else v = fp[cabs - 3];
        At[c0 + u][r] = v;
      }
    }
    {
      int o = t >> 1;
      const float* wp = w1 + (size_t)o * 67;
      int c0 = half * 17;
      int cn = half ? (kn - 17) : 17;
      for (int u = 0; u < cn; u++) Bt[c0 + u][o] = wp[kb + c0 + u];
    }
    __syncthreads();
#pragma unroll 4
    for (int k = 0; k < kn; k++) {
      float4 a0 = *(const float4*)&At[k][ty * 4];
      float4 a1 = *(const float4*)&At[k][ty * 4 + 64];
      float4 b0 = *(const float4*)&Bt[k][tx * 4];
      float4 b1 = *(const float4*)&Bt[k][tx * 4 + 64];
      float av[8] = {a0.x, a0.y, a0.z, a0.w, a1.x, a1.y, a1.z, a1.w};
      float bv[8] = {b0.x, b0.y, b0.z, b0.w, b1.x, b1.y, b1.z, b1.w};
#pragma unroll
      for (int i = 0; i < 8; i++)
#pragma unroll
        for (int j = 0; j < 8; j++) acc[i][j] = fmaf(av[i], bv[j], acc[i][j]);
    }
    __syncthreads();
  }
#pragma unroll
  for (int i = 0; i < 8; i++) {
    int R = ty * 4 + (i & 3) + ((i >> 2) << 6);
    float4 s0 = {acc[i][0], acc[i][1], acc[i][2], acc[i][3]};
    float4 s1 = {acc[i][4], acc[i][5], acc[i][6], acc[i][7]};
    *(float4*)&y1[((size_t)(g0 + R)) * 128 + tx * 4] = s0;
    *(float4*)&y1[((size_t)(g0 + R)) * 128 + tx * 4 + 64] = s1;
  }
  // fused column stats over this block's 128 rows (sum, sumsq per col)
  float s8[8], q8[8];
#pragma unroll
  for (int j = 0; j < 8; j++) {
    float s = 0, q = 0;
#pragma unroll
    for (int i = 0; i < 8; i++) {
      float v = acc[i][j];
      s += v;
      q = fmaf(v, v, q);
    }
    s += __shfl_xor(s, 16); s += __shfl_xor(s, 32);
    q += __shfl_xor(q, 16); q += __shfl_xor(q, 32);
    s8[j] = s; q8[j] = q;
  }
  float* red = &At[0][0];  // reuse: [4][128] sum @0, [4][128] sq @512
  const int wvx = t >> 6;
  if ((t & 63) < 16) {
#pragma unroll
    for (int j = 0; j < 8; j++) {
      int col = tx * 4 + (j & 3) + ((j >> 2) << 6);
      red[wvx * 128 + col] = s8[j];
      red[512 + wvx * 128 + col] = q8[j];
    }
  }
  __syncthreads();
  if (t < 128) {
    float s = red[t] + red[128 + t] + red[256 + t] + red[384 + t];
    float q = red[512 + t] + red[640 + t] + red[768 + t] + red[896 + t];
    statp[(size_t)blockIdx.x * 256 + t] = s;
    statp[(size_t)blockIdx.x * 256 + 128 + t] = q;
  }
}

// ---- G2: affine+relu fused GEMM (K=128,N=256) + channel stats + pool minmax
template <int KS>
__global__ __launch_bounds__(256, 2) void g2_kernel(
    const float* __restrict__ y1, const float* __restrict__ w2,
    const float* __restrict__ a1, const float* __restrict__ b1,
    float* __restrict__ pmin, float* __restrict__ pmax,
    float* __restrict__ statp) {
  __shared__ float At[32][132];
  __shared__ float Bt[32][260];
  const int t = threadIdx.x;
  const int g0 = blockIdx.x * 128;
  const int tx = t & 15, ty = t >> 4;
  float acc[8][16];
#pragma unroll
  for (int i = 0; i < 8; i++)
#pragma unroll
    for (int j = 0; j < 16; j++) acc[i][j] = 0.f;

  const int r = t >> 1, halfA = t & 1;
  const float* arow = y1 + (size_t)(g0 + r) * 128;
  for (int kc = 0; kc < 4; kc++) {
    {
      const int cb = kc * 32 + halfA * 16;
#pragma unroll
      for (int q = 0; q < 4; q++) {
        float4 v = *(const float4*)&arow[cb + q * 4];
        float vv[4] = {v.x, v.y, v.z, v.w};
#pragma unroll
        for (int e = 0; e < 4; e++) {
          int cabs = cb + q * 4 + e;
          float x = fmaxf(fmaf(a1[cabs], vv[e], b1[cabs]), 0.f);
          At[halfA * 16 + q * 4 + e][r] = x;
        }
      }
    }
    {
      const float* wrow = w2 + (size_t)t * 128 + kc * 32;
#pragma unroll
      for (int q = 0; q < 8; q++) {
        float4 w4 = *(const float4*)&wrow[q * 4];
        Bt[q * 4 + 0][t] = w4.x; Bt[q * 4 + 1][t] = w4.y;
        Bt[q * 4 + 2][t] = w4.z; Bt[q * 4 + 3][t] = w4.w;
      }
    }
    __syncthreads();
#pragma unroll 4
    for (int k = 0; k < 32; k++) {
      float4 a0 = *(const float4*)&At[k][ty * 4];
      float4 a1v = *(const float4*)&At[k][ty * 4 + 64];
      float4 b0 = *(const float4*)&Bt[k][tx * 4];
      float4 b1v = *(const float4*)&Bt[k][tx * 4 + 64];
      float4 b2v = *(const float4*)&Bt[k][tx * 4 + 128];
      float4 b3v = *(const float4*)&Bt[k][tx * 4 + 192];
      float av[8] = {a0.x, a0.y, a0.z, a0.w, a1v.x, a1v.y, a1v.z, a1v.w};
      float bv[16] = {b0.x, b0.y, b0.z, b0.w, b1v.x, b1v.y, b1v.z, b1v.w,
                      b2v.x, b2v.y, b2v.z, b2v.w, b3v.x, b3v.y, b3v.z, b3v.w};
#pragma unroll
      for (int i = 0; i < 8; i++)
#pragma unroll
        for (int j = 0; j < 16; j++) acc[i][j] = fmaf(av[i], bv[j], acc[i][j]);
    }
    __syncthreads();
  }

  float* red = &At[0][0];  // 4224 floats >= 2048 needed
  const int w = t >> 6;
  const bool wrsel = ((t & 48) == 0);
  const int NS = 128 / KS;

  // SUM
#pragma unroll
  for (int h = 0; h < 2; h++)
#pragma unroll
    for (int j = 0; j < 16; j++) {
      float x = acc[h * 4][j] + acc[h * 4 + 1][j] + acc[h * 4 + 2][j] + acc[h * 4 + 3][j];
      x += __shfl_xor(x, 16);
      x += __shfl_xor(x, 32);
      if (wrsel) red[(((w << 1) | h) << 8) + (tx << 2) + (j & 3) + ((j >> 2) << 6)] = x;
    }
  __syncthreads();
  float psum = 0;
  for (int e = 0; e < 8; e++) psum += red[(e << 8) + t];
  __syncthreads();
  // SQ
#pragma unroll
  for (int h = 0; h < 2; h++)
#pragma unroll
    for (int j = 0; j < 16; j++) {
      float x = acc[h * 4][j] * acc[h * 4][j];
      x = fmaf(acc[h * 4 + 1][j], acc[h * 4 + 1][j], x);
      x = fmaf(acc[h * 4 + 2][j], acc[h * 4 + 2][j], x);
      x = fmaf(acc[h * 4 + 3][j], acc[h * 4 + 3][j], x);
      x += __shfl_xor(x, 16);
      x += __shfl_xor(x, 32);
      if (wrsel) red[(((w << 1) | h) << 8) + (tx << 2) + (j & 3) + ((j >> 2) << 6)] = x;
    }
  __syncthreads();
  float psq = 0;
  for (int e = 0; e < 8; e++) psq += red[(e << 8) + t];
  statp[(size_t)blockIdx.x * 512 + t] = psum;
  statp[(size_t)blockIdx.x * 512 + 256 + t] = psq;
  __syncthreads();
  // MIN
#pragma unroll
  for (int h = 0; h < 2; h++)
#pragma unroll
    for (int j = 0; j < 16; j++) {
      float x = fminf(fminf(acc[h * 4][j], acc[h * 4 + 1][j]),
                      fminf(acc[h * 4 + 2][j], acc[h * 4 + 3][j]));
      x = fminf(x, __shfl_xor(x, 16));
      x = fminf(x, __shfl_xor(x, 32));
      if (wrsel) red[(((w << 1) | h) << 8) + (tx << 2) + (j & 3) + ((j >> 2) << 6)] = x;
    }
  __syncthreads();
  for (int cell = t; cell < NS * 256; cell += 256) {
    int sg = cell >> 8, col = cell & 255;
    float val;
    if (KS == 16) {
      int h = sg >> 2, ww = sg & 3;
      val = red[(((ww << 1) | h) << 8) + col];
    } else {
      int h = sg >> 1, w0 = (sg & 1) << 1;
      val = fminf(red[(((w0 << 1) | h) << 8) + col],
                  red[((((w0 + 1) << 1) | h) << 8) + col]);
    }
    pmin[(size_t)(blockIdx.x * NS + sg) * 256 + col] = val;
  }
  __syncthreads();
  // MAX
#pragma unroll
  for (int h = 0; h < 2; h++)
#pragma unroll
    for (int j = 0; j < 16; j++) {
      float x = fmaxf(fmaxf(acc[h * 4][j], acc[h * 4 + 1][j]),
                      fmaxf(acc[h * 4 + 2][j], acc[h * 4 + 3][j]));
      x = fmaxf(x, __shfl_xor(x, 16));
      x = fmaxf(x, __shfl_xor(x, 32));
      if (wrsel) red[(((w << 1) | h) << 8) + (tx << 2) + (j & 3) + ((j >> 2) << 6)] = x;
    }
  __syncthreads();
  for (int cell = t; cell < NS * 256; cell += 256) {
    int sg = cell >> 8, col = cell & 255;
    float val;
    if (KS == 16) {
      int h = sg >> 2, ww = sg & 3;
      val = red[(((ww << 1) | h) << 8) + col];
    } else {
      int h = sg >> 1, w0 = (sg & 1) << 1;
      val = fmaxf(red[(((w0 << 1) | h) << 8) + col],
                  red[((((w0 + 1) << 1) | h) << 8) + col]);
    }
    pmax[(size_t)(blockIdx.x * NS + sg) * 256 + col] = val;
  }
}

// ------------- reduce partials -> per-channel affine (a,b) ------------------
__global__ __launch_bounds__(256) void finalize_affine(
    const float* __restrict__ statp, int nb, float invM,
    const float* __restrict__ gamma, const float* __restrict__ beta,
    float* __restrict__ aout, float* __restrict__ bout, int N) {
  const int c = blockIdx.x;
  const int t = threadIdx.x;
  float s = 0, q = 0;
  for (int i = t; i < nb; i += 256) {
    s += statp[(size_t)i * 2 * N + c];
    q += statp[(size_t)i * 2 * N + N + c];
  }
#pragma unroll
  for (int m = 1; m <= 32; m <<= 1) {
    s += __shfl_xor(s, m);
    q += __shfl_xor(q, m);
  }
  __shared__ float rs[4], rq[4];
  if ((t & 63) == 0) { rs[t >> 6] = s; rq[t >> 6] = q; }
  __syncthreads();
  if (t == 0) {
    s = rs[0] + rs[1] + rs[2] + rs[3];
    q = rq[0] + rq[1] + rq[2] + rq[3];
    float mean = s * invM;
    float var = q * invM - mean * mean;
    float ia = gamma[c] * rsqrtf(var + 1e-5f);
    aout[c] = ia;
    bout[c] = beta[c] - mean * ia;
  }
}

// --------- pooled minmax + affine -> concat activation [8192][512] ----------
__global__ __launch_bounds__(256) void pool_concat(
    const float* __restrict__ pmin, const float* __restrict__ pmax,
    const float* __restrict__ a2, const float* __restrict__ b2,
    float* __restrict__ cat, int off) {
  int i = blockIdx.x * 256 + threadIdx.x;
  int row = i >> 8, c = i & 255;
  float a = a2[c];
  float v = (a > 0.f) ? pmax[i] : pmin[i];  // max(relu(a*x+b)) = relu(a*ext+b)
  cat[(size_t)row * 512 + off + c] = fmaxf(fmaf(a, v, b2[c]), 0.f);
}

// ------ fuse GEMMs: M=8192, N=256 (2 col blocks of 128) + FUSED stats -------
template <bool AFF>
__global__ __launch_bounds__(256) void f_kernel(
    const float* __restrict__ A, const float* __restrict__ W,
    const float* __restrict__ ain, const float* __restrict__ bin,
    float* __restrict__ Y, int K, float* __restrict__ statp) {
  __shared__ float At[64][68];
  __shared__ float Bt[64][132];
  const int t = threadIdx.x, tx = t & 15, ty = t >> 4;
  const int g0 = blockIdx.x * 64, cb = blockIdx.y;
  float acc[4][8];
#pragma unroll
  for (int i = 0; i < 4; i++)
#pragma unroll
    for (int j = 0; j < 8; j++) acc[i][j] = 0.f;
  const int rA = t >> 2, qA = t & 3;
  const int oB = t >> 1, hB = t & 1;
  const float* arow = A + (size_t)(g0 + rA) * K + qA * 16;
  const float* wrow = W + (size_t)(cb * 128 + oB) * K + hB * 32;
  for (int kc = 0; kc < K; kc += 64) {
    {
#pragma unroll
      for (int q = 0; q < 4; q++) {
        float4 v = *(const float4*)&arow[kc + q * 4];
        float vv[4] = {v.x, v.y, v.z, v.w};
        if constexpr (AFF) {
          int c = kc + qA * 16 + q * 4;
#pragma unroll
          for (int e = 0; e < 4; e++)
            vv[e] = fmaxf(fmaf(ain[c + e], vv[e], bin[c + e]), 0.f);
        }
#pragma unroll
        for (int e = 0; e < 4; e++) At[qA * 16 + q * 4 + e][rA] = vv[e];
      }
    }
    {
#pragma unroll
      for (int q = 0; q < 8; q++) {
        float4 v = *(const float4*)&wrow[kc + q * 4];
        Bt[hB * 32 + q * 4 + 0][oB] = v.x;
        Bt[hB * 32 + q * 4 + 1][oB] = v.y;
        Bt[hB * 32 + q * 4 + 2][oB] = v.z;
        Bt[hB * 32 + q * 4 + 3][oB] = v.w;
      }
    }
    __syncthreads();
#pragma unroll 8
    for (int k = 0; k < 64; k++) {
      float4 a0 = *(const float4*)&At[k][ty * 4];
      float4 b0 = *(const float4*)&Bt[k][tx * 4];
      float4 b1 = *(const float4*)&Bt[k][tx * 4 + 64];
      float av[4] = {a0.x, a0.y, a0.z, a0.w};
      float bv[8] = {b0.x, b0.y, b0.z, b0.w, b1.x, b1.y, b1.z, b1.w};
#pragma unroll
      for (int i = 0; i < 4; i++)
#pragma unroll
        for (int j = 0; j < 8; j++) acc[i][j] = fmaf(av[i], bv[j], acc[i][j]);
    }
    __syncthreads();
  }
#pragma unroll
  for (int i = 0; i < 4; i++) {
    int R = g0 + ty * 4 + i;
    float4 s0 = {acc[i][0], acc[i][1], acc[i][2], acc[i][3]};
    float4 s1 = {acc[i][4], acc[i][5], acc[i][6], acc[i][7]};
    *(float4*)&Y[(size_t)R * 256 + cb * 128 + tx * 4] = s0;
    *(float4*)&Y[(size_t)R * 256 + cb * 128 + tx * 4 + 64] = s1;
  }
  // fused column stats over this block's 64 rows x 128 cols
  float s8[8], q8[8];
#pragma unroll
  for (int j = 0; j < 8; j++) {
    float s = 0, q = 0;
#pragma unroll
    for (int i = 0; i < 4; i++) {
      float v = acc[i][j];
      s += v;
      q = fmaf(v, v, q);
    }
    s += __shfl_xor(s, 16); s += __shfl_xor(s, 32);
    q += __shfl_xor(q, 16); q += __shfl_xor(q, 32);
    s8[j] = s; q8[j] = q;
  }
  float* red = &At[0][0];  // 4352 floats >= 1024 needed
  const int wvx = t >> 6;
  if ((t & 63) < 16) {
#pragma unroll
    for (int j = 0; j < 8; j++) {
      int col = tx * 4 + (j & 3) + ((j >> 2) << 6);
      red[wvx * 128 + col] = s8[j];
      red[512 + wvx * 128 + col] = q8[j];
    }
  }
  __syncthreads();
  if (t < 128) {
    float s = red[t] + red[128 + t] + red[256 + t] + red[384 + t];
    float q = red[512 + t] + red[640 + t] + red[768 + t] + red[896 + t];
    // N=256 statp layout: row = blockIdx.x, col halves disjoint per cb
    statp[(size_t)blockIdx.x * 512 + cb * 128 + t] = s;
    statp[(size_t)blockIdx.x * 512 + 256 + cb * 128 + t] = q;
  }
}

// ------------------------------ final write --------------------------------
__global__ __launch_bounds__(256) void final_write(
    const float* __restrict__ y, const float* __restrict__ a,
    const float* __restrict__ b, float* __restrict__ out) {
  int i = blockIdx.x * 256 + threadIdx.x;
  int c = i & 255;
  out[i] = fmaxf(fmaf(a[c], y[i], b[c]), 0.f);
}

// ---------------------------------------------------------------------------
// ws layout (float offsets)
static const size_t OFF_IDXFPS = 0;         //  8192 (int)
static const size_t OFF_NEWXYZ = 8192;      // 24576
static const size_t OFF_IDX0 = 32768;       // 131072 (int)
static const size_t OFF_IDX1 = 163840;      // 262144 (int)
static const size_t OFF_Y1 = 425984;        // 33554432
static const size_t OFF_PMIN = 33980416;    // 2097152
static const size_t OFF_PMAX = 36077568;    // 2097152
static const size_t OFF_STATP = 38174720;   // 1048576
static const size_t OFF_CONCAT = 39223296;  // 4194304
static const size_t OFF_YF1 = 43417600;     // 2097152
static const size_t OFF_YF2 = 45514752;     // 2097152
static const size_t OFF_AFF = 47611904;     // 2048

extern "C" void kernel_launch(void* const* d_in, const int* in_sizes, int n_in,
                              void* d_out, int out_size, void* d_ws,
                              size_t ws_size, hipStream_t stream) {
  const float* xyz = (const float*)d_in[0];
  const float* feat = (const float*)d_in[1];
  const float* w1_0 = (const float*)d_in[2];
  const float* g1_0 = (const float*)d_in[3];
  const float* b1_0 = (const float*)d_in[4];
  const float* w2_0 = (const float*)d_in[5];
  const float* g2_0 = (const float*)d_in[6];
  const float* b2_0 = (const float*)d_in[7];
  const float* w1_1 = (const float*)d_in[8];
  const float* g1_1 = (const float*)d_in[9];
  const float* b1_1 = (const float*)d_in[10];
  const float* w2_1 = (const float*)d_in[11];
  const float* g2_1 = (const float*)d_in[12];
  const float* b2_1 = (const float*)d_in[13];
  const float* wf1 = (const float*)d_in[14];
  const float* gf1 = (const float*)d_in[15];
  const float* bf1 = (const float*)d_in[16];
  const float* wf2 = (const float*)d_in[17];
  const float* gf2 = (const float*)d_in[18];
  const float* bf2 = (const float*)d_in[19];

  float* out = (float*)d_out;
  float* ws = (float*)d_ws;

  int* idxfps = (int*)(ws + OFF_IDXFPS);
  float* nx = ws + OFF_NEWXYZ;
  int* idx0 = (int*)(ws + OFF_IDX0);
  int* idx1 = (int*)(ws + OFF_IDX1);
  float* y1 = ws + OFF_Y1;
  float* pmin = ws + OFF_PMIN;
  float* pmax = ws + OFF_PMAX;
  float* statp = ws + OFF_STATP;
  float* cat = ws + OFF_CONCAT;
  float* yf1 = ws + OFF_YF1;
  float* yf2 = ws + OFF_YF2;
  float* a1 = ws + OFF_AFF;
  float* b1 = a1 + 128;
  float* a2 = b1 + 128;
  float* b2 = a2 + 256;
  float* af1 = b2 + 256;
  float* bf1a = af1 + 256;
  float* af2 = bf1a + 256;
  float* bf2a = af2 + 256;

  fps_kernel<<<8, 512, 0, stream>>>(xyz, idxfps, nx, out);
  bq_kernel<<<2048, 256, 0, stream>>>(xyz, nx, idx0, idx1);

  // branch 0 (r=0.1, k=16): M=131072
  g1_kernel<16><<<1024, 256, 0, stream>>>(xyz, feat, nx, idx0, w1_0, y1, statp);
  finalize_affine<<<128, 256, 0, stream>>>(statp, 1024, 1.f / 131072.f, g1_0, b1_0, a1, b1, 128);
  g2_kernel<16><<<1024, 256, 0, stream>>>(y1, w2_0, a1, b1, pmin, pmax, statp);
  finalize_affine<<<256, 256, 0, stream>>>(statp, 1024, 1.f / 131072.f, g2_0, b2_0, a2, b2, 256);
  pool_concat<<<8192, 256, 0, stream>>>(pmin, pmax, a2, b2, cat, 0);

  // branch 1 (r=0.2, k=32): M=262144
  g1_kernel<32><<<2048, 256, 0, stream>>>(xyz, feat, nx, idx1, w1_1, y1, statp);
  finalize_affine<<<128, 256, 0, stream>>>(statp, 2048, 1.f / 262144.f, g1_1, b1_1, a1, b1, 128);
  g2_kernel<32><<<2048, 256, 0, stream>>>(y1, w2_1, a1, b1, pmin, pmax, statp);
  finalize_affine<<<256, 256, 0, stream>>>(statp, 2048, 1.f / 262144.f, g2_1, b2_1, a2, b2, 256);
  pool_concat<<<8192, 256, 0, stream>>>(pmin, pmax, a2, b2, cat, 256);

  // fuse MLP (stats fused into f_kernel)
  f_kernel<false><<<dim3(128, 2), 256, 0, stream>>>(cat, wf1, nullptr, nullptr, yf1, 512, statp);
  finalize_affine<<<256, 256, 0, stream>>>(statp, 128, 1.f / 8192.f, gf1, bf1, af1, bf1a, 256);
  f_kernel<true><<<dim3(128, 2), 256, 0, stream>>>(yf1, wf2, af1, bf1a, yf2, 256, statp);
  finalize_affine<<<256, 256, 0, stream>>>(statp, 128, 1.f / 8192.f, gf2, bf2, af2, bf2a, 256);
  final_write<<<8192, 256, 0, stream>>>(yf2, af2, bf2a, out + 24576);
}